// Round 13
// baseline (1187.177 us; speedup 1.0000x reference)
//
#include <hip/hip_runtime.h>

// Decoder GRU, B=128 T=512 X=64 H=256, skip runtime (skip==0 -> generic
// path).  Round 19: NT=1024 -- double TLP (4 waves/SIMD), same math.
//
// R12-R18 ledger: conflicts->0 (null), vmcnt-free barrier (null), LDS-byte
// cut (regress), 2-batch ILP (regress), pk_fma swap (null -> dot2 is full
// rate).  No resource saturated; step = 4870 cyc vs max(VALU ~1500,
// LDS ~2200) -> latency bubbles that 2 phase-locked waves/SIMD can't fill.
// The untouched axis is TLP.  This round: NT=1024, thread = (col c=t>>2,
// K-quarter kq=t&3), waves_per_eu(4,4) -> 128-reg budget, 16 waves/CU:
//   regs: whh r,z 16u4=64 + wih 6u4=24 + wout 2u4=8 (+~30 working) <= 128
//   LDS:  wn n-gate stream 128 KB [j][t] (per-lane b128, conflict-free),
//         ring fp32 16 KB, hid4/xt4/pt2 staggered blocks (R15-verified
//         pattern: kq-blocks stride 36/12/12 words -> disjoint bank quads),
//         masks 4 KB.  Total ~151 KB.
// Work per CU conserved (120 dot2/thread x 16 waves); 4 waves/SIMD now
// interleave LDS waits with dots.  1 lgkm-only barrier/step (R14 pattern).
// Reduce = DPP quad butterfly (xor1+xor2); PROJ reduce adds shfl 4/8.
typedef _Float16 h2_t __attribute__((ext_vector_type(2)));

constexpr int T_ = 512;
constexpr int X_ = 64;
constexpr int H_ = 256;
constexpr int NWG = 128;   // 1 batch per WG, 1 WG/CU
constexpr int NT = 1024;   // 16 waves = 4/EU
constexpr int RS = 16;     // ring slots; lookback 2*skip, OK for skip <= 7

// fp16 weight image in d_ws (uint4 units), [u][t], c=t>>2, kq=t&3:
//   u  0..15 : W_hh r,z (g=u>>3, j=u&7) row g*256+c, k = kq*64+j*8
//   u 16..23 : W_hh n   (j=u-16)        row 512+c,   k = kq*64+j*8
//   u 24..29 : W_ih     (g=(u-24)>>1, j=(u-24)&1)    k = kq*16+j*8
//   u 30..31 : W_out    (j=u-30; xc=t>>4, sl=t&15)   k = sl*16+j*8
constexpr int G_TOTAL = 32 * NT;  // 32768 uint4 = 512 KB

__device__ __forceinline__ float sigmoid_f(float x) {
  float e = __expf(fminf(-x, 80.f));
  return 1.f / (1.f + e);
}
__device__ __forceinline__ float tanh_f(float x) {
  float e = __expf(fminf(-2.f * x, 80.f));
  return (1.f - e) / (1.f + e);
}

__device__ __forceinline__ unsigned pk2(float a, float b) {
  h2_t v;
  v[0] = (_Float16)a;
  v[1] = (_Float16)b;
  return __builtin_bit_cast(unsigned, v);
}
__device__ __forceinline__ uint4 pk8(const float* s) {
  return make_uint4(pk2(s[0], s[1]), pk2(s[2], s[3]), pk2(s[4], s[5]),
                    pk2(s[6], s[7]));
}

// fp16-pair dot with fp32 accumulate (v_dot2_f32_f16, full-rate per R18)
__device__ __forceinline__ float dotp(unsigned w, unsigned h, float acc) {
  h2_t wv = __builtin_bit_cast(h2_t, w);
  h2_t hv = __builtin_bit_cast(h2_t, h);
#if __has_builtin(__builtin_amdgcn_fdot2)
  return __builtin_amdgcn_fdot2(wv, hv, acc, false);
#else
  acc = fmaf((float)wv[0], (float)hv[0], acc);
  return fmaf((float)wv[1], (float)hv[1], acc);
#endif
}
__device__ __forceinline__ float dotq(uint4 w, uint4 h, float acc) {
  acc = dotp(w.x, h.x, acc);
  acc = dotp(w.y, h.y, acc);
  acc = dotp(w.z, h.z, acc);
  acc = dotp(w.w, h.w, acc);
  return acc;
}

// DPP quad_perm: xor1 = 0xB1, xor2 = 0x4E (VALU-only lane exchange)
__device__ __forceinline__ float dpp_xor1(float x) {
  int v = __builtin_amdgcn_update_dpp(0, __builtin_bit_cast(int, x), 0xB1,
                                      0xF, 0xF, true);
  return __builtin_bit_cast(float, v);
}
__device__ __forceinline__ float dpp_xor2(float x) {
  int v = __builtin_amdgcn_update_dpp(0, __builtin_bit_cast(int, x), 0x4E,
                                      0xF, 0xF, true);
  return __builtin_bit_cast(float, v);
}
// quad reduce: all 4 kq lanes end with the quad sum
#define QRED(v)                                                              \
  v += dpp_xor1(v);                                                          \
  v += dpp_xor2(v);

// Main-loop barrier: LDS-only drain, no vmcnt (out[] stores never read back)
__device__ __forceinline__ void bar_lds() {
  asm volatile("s_waitcnt lgkmcnt(0)\n\ts_barrier" ::: "memory");
}

// One-time fp32 -> fp16 pack + transpose into the new layouts.
__global__ void prep_kernel(const float* __restrict__ Wih,
                            const float* __restrict__ Whh,
                            const float* __restrict__ Wout,
                            uint4* __restrict__ G) {
  int id = blockIdx.x * 256 + threadIdx.x;
  if (id >= G_TOTAL) return;
  int t = id & (NT - 1), u = id >> 10;
  int c = t >> 2, kq = t & 3;
  if (u < 16) {  // W_hh r,z
    int g = u >> 3, j = u & 7;
    G[id] = pk8(Whh + (size_t)(g * 256 + c) * H_ + kq * 64 + j * 8);
  } else if (u < 24) {  // W_hh n (LDS stream)
    int j = u - 16;
    G[id] = pk8(Whh + (size_t)(512 + c) * H_ + kq * 64 + j * 8);
  } else if (u < 30) {  // W_ih
    int v = u - 24, g = v >> 1, j = v & 1;
    G[id] = pk8(Wih + (size_t)(g * 256 + c) * X_ + kq * 16 + j * 8);
  } else {  // W_out
    int j = u - 30, xc = t >> 4, sl = t & 15;
    G[id] = pk8(Wout + (size_t)xc * H_ + sl * 16 + j * 8);
  }
}

// LDS state layouts (words):
//  hid4: 4 kq-blocks x 36 (32 data + 4 stagger); h[k] at (k>>6)*36+((k&63)>>1)
//  xt4 : 4 kq-blocks x 12 (8 data + 4);          x[k] at (k>>4)*12+((k&15)>>1)
//  pt2 : 16 sl-blocks x 12 (8 data + 4);        pt[k] at (k>>4)*12+((k&15)>>1)
#define HW_(k) (((k) >> 6) * 36 + (((k)&63) >> 1))
#define XW_(k) (((k) >> 4) * 12 + (((k)&15) >> 1))

// ---- per-step bodies (assign pre-declared hn / fa; p,q compile-time) ----

#define GATES_BODY(p, i)                                                     \
  {                                                                          \
    float ar = 0, az = 0, an = 0, ni = 0;                                    \
    const uint4* h4 = ((const uint4*)hid4[p]) + kq * 9;                      \
    _Pragma("unroll") for (int j = 0; j < 8; ++j) {                          \
      uint4 hj = h4[j];                                                      \
      uint4 wnj = wn[j * NT + t];                                            \
      ar = dotq(wrz[j], hj, ar);                                             \
      az = dotq(wrz[8 + j], hj, az);                                         \
      an = dotq(wnj, hj, an);                                                \
    }                                                                        \
    const uint4* x4 = ((const uint4*)xt4[p]) + kq * 3;                       \
    {                                                                        \
      uint4 xa = x4[0], xb = x4[1];                                          \
      ar = dotq(wih[0], xa, ar);                                             \
      ar = dotq(wih[1], xb, ar);                                             \
      az = dotq(wih[2], xa, az);                                             \
      az = dotq(wih[3], xb, az);                                             \
      ni = dotq(wih[4], xa, ni);                                             \
      ni = dotq(wih[5], xb, ni);                                             \
    }                                                                        \
    QRED(ar)                                                                 \
    QRED(az)                                                                 \
    QRED(an)                                                                 \
    QRED(ni)                                                                 \
    float r = sigmoid_f(ar + bsr);                                           \
    float z = sigmoid_f(az + bsz);                                           \
    float n = tanh_f(ni + bin_ + r * (an + bhn_));                           \
    hn = fmaf(z, hid_reg - n, n); /* (1-z)*n + z*hidden */                   \
    if ((t & 3) == 0) ring[(i) & (RS - 1)][c] = hn;                          \
  }

#define PROJ_DOTS_BODY(p)                                                    \
  {                                                                          \
    const uint4* p4 = (const uint4*)&pt2[p][sl * 12];                        \
    fa = dotq(wout[0], p4[0], 0.f);                                          \
    fa = dotq(wout[1], p4[1], fa);                                           \
  }

#define PROJ_FIN(q, i)                                                       \
  {                                                                          \
    fa += dpp_xor1(fa);                                                      \
    fa += dpp_xor2(fa);                                                      \
    fa += __shfl_xor(fa, 4);                                                 \
    fa += __shfl_xor(fa, 8);                                                 \
    float o = fa + bo;                                                       \
    if ((t & 15) == 0) out[ob + (size_t)(i)*X_ + xc] = o;                    \
    float oo = __shfl_xor(o, 16);                                            \
    if ((t & 31) == 0) xt4[q][XW_(xc)] = pk2(o, oo);                         \
  }

// Main-loop step (i >= 2*skip, skip >= 1): pt2[p] made at step i-1; PROJ is
// independent of GATES(i) -> its dots issue first to fill load latency.
#define MSTEP(i, p, q)                                                       \
  {                                                                          \
    float hn, fa;                                                            \
    PROJ_DOTS_BODY(p)                                                        \
    GATES_BODY(p, i)                                                         \
    PROJ_FIN(q, i)                                                           \
    if ((i) + 1 < T_) {                                                      \
      float sg = ring[((i) + 1 - 2 * skip) & (RS - 1)][c];                   \
      float hidn = m0f[(i) + 1] * hn + m1f[(i) + 1] * sg;                    \
      float ptn = hn + sg;                                                   \
      hid_reg = hidn;                                                        \
      float ho = __shfl_xor(hidn, 4);                                        \
      float po = __shfl_xor(ptn, 4);                                         \
      if ((t & 7) == 0) {                                                    \
        hid4[q][HW_(c)] = pk2(hidn, ho);                                     \
        pt2[q][XW_(c)] = pk2(ptn, po);                                       \
      }                                                                      \
    }                                                                        \
    bar_lds();                                                               \
  }

__global__ __attribute__((amdgpu_flat_work_group_size(NT, NT),
                          amdgpu_waves_per_eu(4, 4))) void decoder_kernel(
    const float* __restrict__ h_enc, const float* __restrict__ b_ih,
    const float* __restrict__ b_hh, const float* __restrict__ b_out,
    const int* __restrict__ mask0, const int* __restrict__ mask1,
    const int* __restrict__ skipp, const uint4* __restrict__ G,
    float* __restrict__ out) {
  __shared__ alignas(16) uint4 wn[8 * NT];       // 128 KB W_hh n-gate [j][t]
  __shared__ float ring[RS][H_];                 // 16 KB h history (fp32)
  __shared__ alignas(16) unsigned hid4[2][144];  // fp16 h, 4 blk x 36 w
  __shared__ alignas(16) unsigned pt2[2][192];   // fp16 h_prev+skip, 16 x 12
  __shared__ alignas(16) unsigned xt4[2][48];    // fp16 x, 4 blk x 12 w
  __shared__ float m0f[T_], m1f[T_];             // 4 KB masks
  // total: 131072+16384+1152+1536+384+4096 = 154624 B (151 KB)

  const int t = threadIdx.x;
  const int b = blockIdx.x;
  const int c = t >> 2, kq = t & 3;    // gate role: column, K-quarter
  const int xc = t >> 4, sl = t & 15;  // projection role
  const size_t ob = (size_t)b * T_ * X_;

  // ---- resident weight registers: 24 uint4 = 96 regs/thread ----
  uint4 wrz[16];  // r,z gates, 64 k each
  uint4 wih[6];   // 3 gates x 16 k
  uint4 wout[2];  // 16 k-slice of own xc column
#pragma unroll
  for (int u = 0; u < 16; ++u) wrz[u] = G[u * NT + t];
#pragma unroll
  for (int u = 0; u < 6; ++u) wih[u] = G[(24 + u) * NT + t];
#pragma unroll
  for (int u = 0; u < 2; ++u) wout[u] = G[(30 + u) * NT + t];

  // ---- LDS: n-gate weights + masks ----
#pragma unroll
  for (int u = 0; u < 8; ++u) wn[u * NT + t] = G[(16 + u) * NT + t];
  if (t < T_) {
    m0f[t] = (float)mask0[t];
    m1f[t] = (float)mask1[t];
  }

  const int skip = skipp[0];
  const int i0 = (skip == 0) ? T_ : ((2 * skip < T_) ? 2 * skip : T_);

  const float bsr = b_ih[c] + b_hh[c];
  const float bsz = b_ih[H_ + c] + b_hh[H_ + c];
  const float bin_ = b_ih[2 * H_ + c];
  const float bhn_ = b_hh[2 * H_ + c];
  const float bo = b_out[xc];

  float hp = h_enc[(size_t)b * H_ + c];
  float hid_reg = (float)mask0[0] * hp;  // hidden(0); skip_g(0) == 0
  float hps_reg = hp;                    // h_prev(0) = h_enc
  {
    float ho = __shfl_xor(hid_reg, 4);
    if ((t & 7) == 0) hid4[0][HW_(c)] = pk2(hid_reg, ho);
  }
  if (t < 48) xt4[0][t] = 0u;  // GO token
  __syncthreads();

  // ---- prologue: generic 2-barrier steps for i < 2*skip ----
  for (int i = 0; i < i0; ++i) {
    const int p = i & 1, q = p ^ 1;
    float hn, fa;
    GATES_BODY(p, i)
    {
      int ppos = (i < skip) ? 2 * i + 1 : i - skip;
      bool pz = ppos < skip;
      int pi = ppos - skip;
      if (pi < 0) pi = 0;
      float sp = pz ? 0.f : ((pi == i) ? hn : ring[pi & (RS - 1)][c]);
      float ptv = hps_reg + sp;
      float po = __shfl_xor(ptv, 4);
      if ((t & 7) == 0) pt2[p][XW_(c)] = pk2(ptv, po);
    }
    if (i + 1 < T_) {
      int i1 = i + 1;
      int pg = (i1 < skip) ? 2 * i1 : i1 - skip;
      bool gz = pg < skip;
      int gi = pg - skip;
      if (gi < 0) gi = 0;
      if (gi >= i1) gz = true;  // unwritten slot == reference zero init
      float sg = gz ? 0.f : ((gi == i) ? hn : ring[gi & (RS - 1)][c]);
      float hidn = m0f[i1] * hn + m1f[i1] * sg;
      hid_reg = hidn;
      float ho = __shfl_xor(hidn, 4);
      if ((t & 7) == 0) hid4[q][HW_(c)] = pk2(hidn, ho);
      if (skip > 0 && i1 >= 2 * skip) {  // handoff into fused main loop
        float sgp = ring[(i1 - 2 * skip) & (RS - 1)][c];
        float ptn = hn + sgp;
        float po2 = __shfl_xor(ptn, 4);
        if ((t & 7) == 0) pt2[q][XW_(c)] = pk2(ptn, po2);
      }
    }
    hps_reg = hn;
    __syncthreads();
    PROJ_DOTS_BODY(p)
    PROJ_FIN(q, i)
    __syncthreads();
  }

  // ---- main loop: one lgkm-only barrier per step; i0 even -> parity static
#pragma unroll 1
  for (int i = i0; i < T_; i += 2) {
    MSTEP(i, 0, 1)
    MSTEP(i + 1, 1, 0)
  }
}

extern "C" void kernel_launch(void* const* d_in, const int* in_sizes, int n_in,
                              void* d_out, int out_size, void* d_ws,
                              size_t ws_size, hipStream_t stream) {
  (void)in_sizes; (void)n_in; (void)out_size; (void)ws_size;
  // d_in[0] = input [B,T,X] — unused by the reference computation.
  const float* h_enc = (const float*)d_in[1];
  const float* W_ih = (const float*)d_in[2];
  const float* W_hh = (const float*)d_in[3];
  const float* b_ih = (const float*)d_in[4];
  const float* b_hh = (const float*)d_in[5];
  const float* W_out = (const float*)d_in[6];
  const float* b_out = (const float*)d_in[7];
  const int* mask0 = (const int*)d_in[8];
  const int* mask1 = (const int*)d_in[9];
  const int* skipp = (const int*)d_in[10];
  float* out = (float*)d_out;
  uint4* G = (uint4*)d_ws;  // 512 KB fp16 weight image

  prep_kernel<<<dim3(G_TOTAL / 256), dim3(256), 0, stream>>>(W_ih, W_hh,
                                                             W_out, G);
  decoder_kernel<<<dim3(NWG), dim3(NT), 0, stream>>>(
      h_enc, b_ih, b_hh, b_out, mask0, mask1, skipp, G, out);
}